// Round 6
// baseline (827.181 us; speedup 1.0000x reference)
//
#include <hip/hip_runtime.h>

// ======================================================================
// Involution net: 3 x (1x1 conv + dynamic-kernel apply w/ batch BN) + FC
// B=1024, fp32 reference.
//
// R9 == R8 resubmitted verbatim after line-audit (broker timeout gave no
// data). R8 design: amortize fixed costs (R7 post-mortem: f2 230us
// regression proved per-block time is stage+barrier-dominated).
//  * f2/f3: nb=2 batches per block (grid 512). Weight M-half staged ONCE
//    and reused across full K loop and both batches. rl phase fused into
//    kernel-gen; BN applied on the fly.
//  * f4: R6 form (known ~151us).
//  * p1: R7 coalesced-staging MFMA version.
// Per-output FMA accumulation order unchanged -> arithmetic identical
// to the passing R6/R7 runs (absmax 0.0625).
// ======================================================================

typedef __attribute__((ext_vector_type(8))) short short8v;   // 8 bf16 bit-patterns
typedef __attribute__((ext_vector_type(4))) float f32x4;

__device__ __forceinline__ unsigned short f2bf_rne(float x) {
    unsigned u = __float_as_uint(x);
    unsigned r = u + 0x7FFFu + ((u >> 16) & 1u);
    return (unsigned short)(r >> 16);
}
__device__ __forceinline__ float bf2f(unsigned short h) {
    return __uint_as_float(((unsigned)h) << 16);
}

static constexpr size_t OFF_WCAT1 = 0;        // unused by MFMA path (kept)
static constexpr size_t OFF_WCAT2 = 25600;
static constexpr size_t OFF_WCAT3 = 41984;
static constexpr size_t OFF_SUM1  = 107520;
static constexpr size_t OFF_SQS1  = 107584;
static constexpr size_t OFF_SUM2  = 107648;
static constexpr size_t OFF_SQS2  = 107776;
static constexpr size_t OFF_SUM3  = 107904;
static constexpr size_t OFF_SQS3  = 108160;
static constexpr size_t OFF_XI1   = 108416;     // 16777216 floats (also xi3)
static constexpr size_t OFF_RPRE1 = 16885632;   //  4194304 floats (also rpre3)
static constexpr size_t OFF_XI2   = 21079936;   //  8388608 floats
static constexpr size_t OFF_RPRE2 = 29468544;   //  2097152 floats -> end 31565696
static constexpr size_t OFF_APKH  = OFF_XI2;            // aliases xi2 (dead then)
static constexpr size_t OFF_APKL  = OFF_XI2 + 14336;

// ---------------- weight concat+transpose prep + stat zero ----------------
__global__ void prep_all(const float* __restrict__ wi1, const float* __restrict__ wr1,
                         const float* __restrict__ wi2, const float* __restrict__ wr2,
                         const float* __restrict__ wi3, const float* __restrict__ wr3,
                         float* __restrict__ ws) {
    int e = blockIdx.x * 256 + threadIdx.x;
    if (e >= 108416) return;
    if (e >= 107520) { ws[e] = 0.f; return; }     // BN stat accumulators
    const float* wi; const float* wr; float* wt; int cin, cout;
    if (e < 25600)      { wi = wi1; wr = wr1; wt = ws + OFF_WCAT1; cin = 200; cout = 64; }
    else if (e < 41984) { e -= 25600; wi = wi2; wr = wr2; wt = ws + OFF_WCAT2; cin = 64;  cout = 128; }
    else                { e -= 41984; wi = wi3; wr = wr3; wt = ws + OFF_WCAT3; cin = 128; cout = 256; }
    int M = 2 * cout, c = e / M, m = e % M;
    wt[e] = (m < cout) ? wi[m * cin + c] : wr[(m - cout) * cin + c];
}

// ---------------- A-fragment packing for p1_l1 MFMA ----------------
__global__ void prep_apk(const float* __restrict__ wi1, const float* __restrict__ wr1,
                         unsigned short* __restrict__ ah, unsigned short* __restrict__ al) {
    int e = blockIdx.x * 256 + threadIdx.x;
    if (e >= 28672) return;
    int v  = e & 7;
    int l  = (e >> 3) & 63;
    int mt = (e >> 9) & 7;
    int ck = e >> 12;
    int c = 32 * ck + ((l >> 4) << 3) + v;
    int m = 16 * mt + (l & 15);
    float wv = 0.f;
    if (c < 200) wv = (m < 64) ? wi1[m * 200 + c] : wr1[(m - 64) * 200 + c];
    unsigned short h = f2bf_rne(wv);
    ah[e] = h;
    al[e] = f2bf_rne(wv - bf2f(h));
}

// ---------------- P1 layer 1 via split-bf16 MFMA (R7 version) ----------------
__global__ __launch_bounds__(512) void p1_l1_mfma(
    const float* __restrict__ x,      // [B][200][256]
    const unsigned short* __restrict__ aHiG,
    const unsigned short* __restrict__ aLoG,
    float* __restrict__ xi,           // [B][64][256]
    float* __restrict__ rpre,         // [B][64][64]
    float* __restrict__ ssum, float* __restrict__ ssqs)
{
    __shared__ float xf[4096];                          // [32][128] fp32, src-swizzled
    __shared__ __align__(16) unsigned short bHi[4096];  // 512 slots x 8 bf16
    __shared__ __align__(16) unsigned short bLo[4096];
    const int tid = threadIdx.x;
    const int b = blockIdx.x >> 1, half = blockIdx.x & 1;
    const int lane = tid & 63, w = tid >> 6;
    const int n0 = 128 * half;
    const float* xb = x + (size_t)b * 200 * 256;

    f32x4 acc[8];
    #pragma unroll
    for (int i = 0; i < 8; ++i) acc[i] = f32x4{0.f, 0.f, 0.f, 0.f};

    const int row0 = tid >> 5;            // 0..15
    const int col4 = tid & 31;
    const int c4x  = col4 ^ (((row0 >> 3) & 1) << 2);
    const float* src0 = xb + n0 + 4 * c4x + (size_t)row0 * 256;
    const float* src1 = src0 + (size_t)16 * 256;

    auto ldg = [&](const float* p, int c) -> float4 {
        return (c < 200) ? *(const float4*)p : float4{0.f, 0.f, 0.f, 0.f};
    };

    const int ntl_s = tid >> 6, l_s = tid & 63, g_s = l_s >> 4;
    const int qx = (16 * ntl_s + (l_s & 15)) ^ ((g_s & 1) << 4);
    const int grow = 8 * g_s;

    float4 r0 = ldg(src0, row0), r1 = ldg(src1, row0 + 16);

    for (int ck = 0; ck < 7; ++ck) {
        ((float4*)xf)[row0 * 32 + col4] = r0;
        ((float4*)xf)[(row0 + 16) * 32 + col4] = r1;
        __syncthreads();
        if (ck < 6) {
            int c0n = 32 * (ck + 1);
            r0 = ldg(src0 + (size_t)c0n * 256, c0n + row0);
            r1 = ldg(src1 + (size_t)c0n * 256, c0n + row0 + 16);
        }
        {
            unsigned short h[8], g8[8];
            #pragma unroll
            for (int j = 0; j < 8; ++j) {
                float v = xf[(grow + j) * 128 + qx];
                h[j] = f2bf_rne(v);
                g8[j] = f2bf_rne(v - bf2f(h[j]));
            }
            uint4 ph, pl;
            ph.x = (unsigned)h[0] | ((unsigned)h[1] << 16);
            ph.y = (unsigned)h[2] | ((unsigned)h[3] << 16);
            ph.z = (unsigned)h[4] | ((unsigned)h[5] << 16);
            ph.w = (unsigned)h[6] | ((unsigned)h[7] << 16);
            pl.x = (unsigned)g8[0] | ((unsigned)g8[1] << 16);
            pl.y = (unsigned)g8[2] | ((unsigned)g8[3] << 16);
            pl.z = (unsigned)g8[4] | ((unsigned)g8[5] << 16);
            pl.w = (unsigned)g8[6] | ((unsigned)g8[7] << 16);
            *(uint4*)(bHi + (size_t)tid * 8) = ph;
            *(uint4*)(bLo + (size_t)tid * 8) = pl;
        }
        __syncthreads();
        const size_t abase = ((size_t)(ck * 8 + w) * 64 + lane) * 8;
        short8v aH = *(const short8v*)(aHiG + abase);
        short8v aL = *(const short8v*)(aLoG + abase);
        #pragma unroll
        for (int nt = 0; nt < 8; ++nt) {
            short8v bH = *(const short8v*)(bHi + ((size_t)(nt * 64 + lane)) * 8);
            short8v bL = *(const short8v*)(bLo + ((size_t)(nt * 64 + lane)) * 8);
            acc[nt] = __builtin_amdgcn_mfma_f32_16x16x32_bf16(aH, bH, acc[nt], 0, 0, 0);
            acc[nt] = __builtin_amdgcn_mfma_f32_16x16x32_bf16(aH, bL, acc[nt], 0, 0, 0);
            acc[nt] = __builtin_amdgcn_mfma_f32_16x16x32_bf16(aL, bH, acc[nt], 0, 0, 0);
        }
    }

    const int g = lane >> 4, col = lane & 15;
    if (w < 4) {
        float* xr = xi + ((size_t)b * 64 + 16 * w + 4 * g) * 256 + n0 + col;
        #pragma unroll
        for (int r = 0; r < 4; ++r)
            #pragma unroll
            for (int nt = 0; nt < 8; ++nt)
                xr[(size_t)r * 256 + nt * 16] = acc[nt][r];
    } else {
        #pragma unroll
        for (int r = 0; r < 4; ++r) {
            const int mr = 16 * (w - 4) + 4 * g + r;
            float pv[4], s1 = 0.f, s2 = 0.f;
            #pragma unroll
            for (int p = 0; p < 4; ++p) {
                float a0 = acc[2 * p][r], a1 = acc[2 * p + 1][r];
                float pp = 0.25f * (a0 + __shfl_xor(a0, 1) + a1 + __shfl_xor(a1, 1));
                pv[p] = pp; s1 += pp; s2 += pp * pp;
            }
            if ((col & 1) == 0) {
                float* rp = rpre + ((size_t)b * 64 + mr) * 64 + (col >> 1);
                #pragma unroll
                for (int p = 0; p < 4; ++p) rp[(4 * half + p) * 8] = pv[p];
            }
            s1 += __shfl_xor(s1, 2); s2 += __shfl_xor(s2, 2);
            s1 += __shfl_xor(s1, 4); s2 += __shfl_xor(s2, 4);
            s1 += __shfl_xor(s1, 8); s2 += __shfl_xor(s2, 8);
            if (col == 0) { atomicAdd(ssum + mr, s1); atomicAdd(ssqs + mr, s2); }
        }
    }
}

// ---------------- F2: p3(layer1) + p1_l2, nb=2 batches/block, grid 512 --------
// Phases: BN -> fused kgen(BN+ReLU from global rpre1) -> apply ->
// for mh in 0,1: stage Ws[64][128] once; barrier-free K=64 loop per batch.
__global__ __launch_bounds__(256) void f2_kernel(
    const float* __restrict__ xi1,    // [B][64][256]
    const float* __restrict__ rpre1,  // [B][64][64]
    const float* __restrict__ ssum1, const float* __restrict__ ssqs1,
    const float* __restrict__ gamma1, const float* __restrict__ beta1,
    const float* __restrict__ wspan1, // [4][64]
    const float* __restrict__ wT2,    // [64][256]
    float* __restrict__ xi2,          // [B][128][64]
    float* __restrict__ rpre2,        // [B][128][16]
    float* __restrict__ ssum2, float* __restrict__ ssqs2)
{
    __shared__ float sc[64], sh[64];
    __shared__ float kl[2][4][64];
    __shared__ float Xl[2][64][64];   // out1 for 2 batches, 32KB
    __shared__ float Ws[64][128];     // wT2 M-half, 32KB
    const int tid = threadIdx.x;
    const int b0 = blockIdx.x * 2;

    if (tid < 64) {
        float mean = ssum1[tid] * (1.f / 65536.f);
        float var  = ssqs1[tid] * (1.f / 65536.f) - mean * mean;
        float s    = gamma1[tid] * rsqrtf(var + 1e-5f);
        sc[tid] = s; sh[tid] = beta1[tid] - mean * s;
    }
    __syncthreads();

    // fused BN+ReLU+kernel-gen: 2b x 4kk x 64q = 512 tasks, 2/thread
    #pragma unroll
    for (int t = 0; t < 2; ++t) {
        int task = tid + t * 256;
        int bb = task >> 8, kk = (task >> 6) & 3, q = task & 63;
        const float* rp = rpre1 + (size_t)(b0 + bb) * 4096;
        float s = 0.f;
        #pragma unroll
        for (int o = 0; o < 64; ++o)
            s = fmaf(wspan1[kk * 64 + o],
                     fmaxf(fmaf(sc[o], rp[o * 64 + q], sh[o]), 0.f), s);
        kl[bb][kk][q] = s;
    }
    __syncthreads();

    // apply k=2,s=2 on 16x16 -> Xl[bb][64][64]
    #pragma unroll
    for (int bb = 0; bb < 2; ++bb) {
        const float* xb1 = xi1 + (size_t)(b0 + bb) * 64 * 256;
        for (int e = tid; e < 4096; e += 256) {
            int o = e >> 6, q = e & 63, ho = q >> 3, wo = q & 7;
            const float* p = xb1 + ((size_t)(o * 16 + 2 * ho)) * 16 + 2 * wo;
            float2 t  = *(const float2*)p;
            float2 bo = *(const float2*)(p + 16);
            Xl[bb][o][q] = kl[bb][0][q] * t.x + kl[bb][1][q] * t.y
                         + kl[bb][2][q] * bo.x + kl[bb][3][q] * bo.y;
        }
    }
    __syncthreads();

    const int tn = tid & 7, tm = tid >> 3;   // tm 0..31: rows tm*4..+3 of M-half
    for (int mh = 0; mh < 2; ++mh) {
        if (mh) __syncthreads();             // protect Ws reuse
        for (int e4 = tid; e4 < 2048; e4 += 256) {
            int c = e4 >> 5, col4 = e4 & 31;
            ((float4*)Ws)[e4] = *(const float4*)(wT2 + (size_t)c * 256 + mh * 128 + col4 * 4);
        }
        __syncthreads();
        #pragma unroll
        for (int bb = 0; bb < 2; ++bb) {
            const int b = b0 + bb;
            float acc[4][8];
            #pragma unroll
            for (int i = 0; i < 4; ++i)
                #pragma unroll
                for (int j = 0; j < 8; ++j) acc[i][j] = 0.f;
            for (int c = 0; c < 64; ++c) {
                float4 xa = *(const float4*)(&Xl[bb][c][tn * 4]);
                float4 xc = *(const float4*)(&Xl[bb][c][32 + tn * 4]);
                float4 wa = *(const float4*)(&Ws[c][tm * 4]);
                float xfv[8] = {xa.x, xa.y, xa.z, xa.w, xc.x, xc.y, xc.z, xc.w};
                float wf[4] = {wa.x, wa.y, wa.z, wa.w};
                #pragma unroll
                for (int i = 0; i < 4; ++i)
                    #pragma unroll
                    for (int j = 0; j < 8; ++j)
                        acc[i][j] = fmaf(wf[i], xfv[j], acc[i][j]);
            }
            if (mh == 0) {   // xi2 rows tm*4+i
                #pragma unroll
                for (int i = 0; i < 4; ++i) {
                    float* dst = xi2 + ((size_t)b * 128 + tm * 4 + i) * 64 + tn * 4;
                    *(float4*)dst = float4{acc[i][0], acc[i][1], acc[i][2], acc[i][3]};
                    *(float4*)(dst + 32) = float4{acc[i][4], acc[i][5], acc[i][6], acc[i][7]};
                }
            } else {         // red rows -> pool + stats (R6 epilogue verbatim)
                const bool val = (tn & 2) == 0;
                #pragma unroll
                for (int i = 0; i < 4; ++i) {
                    const int mr = tm * 4 + i;
                    float hp0 = acc[i][0] + acc[i][1], hp1 = acc[i][2] + acc[i][3];
                    float hp2 = acc[i][4] + acc[i][5], hp3 = acc[i][6] + acc[i][7];
                    float p0 = 0.25f * (hp0 + __shfl_xor(hp0, 2));
                    float p1 = 0.25f * (hp1 + __shfl_xor(hp1, 2));
                    float p2 = 0.25f * (hp2 + __shfl_xor(hp2, 2));
                    float p3 = 0.25f * (hp3 + __shfl_xor(hp3, 2));
                    float s1 = val ? (p0 + p1 + p2 + p3) : 0.f;
                    float s2 = val ? (p0 * p0 + p1 * p1 + p2 * p2 + p3 * p3) : 0.f;
                    if (val) {
                        const int wo = (tn & 1) * 2, ho = tn >> 2;
                        float* rp = rpre2 + ((size_t)b * 128 + mr) * 16;
                        *(float2*)(rp + ho * 4 + wo) = float2{p0, p1};
                        *(float2*)(rp + (2 + ho) * 4 + wo) = float2{p2, p3};
                    }
                    #pragma unroll
                    for (int off = 1; off <= 4; off <<= 1) {
                        s1 += __shfl_xor(s1, off); s2 += __shfl_xor(s2, off);
                    }
                    if (tn == 0) { atomicAdd(ssum2 + mr, s1); atomicAdd(ssqs2 + mr, s2); }
                }
            }
        }
    }
}

// ---------------- F3: p3(layer2) + p1_l3, nb=2 batches/block, grid 512 --------
__global__ __launch_bounds__(256) void f3_kernel(
    const float* __restrict__ xi2,    // [B][128][64]
    const float* __restrict__ rpre2,  // [B][128][16]
    const float* __restrict__ ssum2, const float* __restrict__ ssqs2,
    const float* __restrict__ gamma2, const float* __restrict__ beta2,
    const float* __restrict__ wspan2, // [4][128]
    const float* __restrict__ wT3,    // [128][512]
    float* __restrict__ xi3,          // [B][256][16]
    float* __restrict__ rpre3,        // [B][256][16]
    float* __restrict__ ssum3, float* __restrict__ ssqs3)
{
    __shared__ float sc[128], sh[128];
    __shared__ float kl[2][4][16];
    __shared__ float Xl[2][128][16];  // out2 for 2 batches, 16KB
    __shared__ float Ws[32][256];     // wT3 slice, 32KB
    const int tid = threadIdx.x;
    const int b0 = blockIdx.x * 2;

    if (tid < 128) {
        float mean = ssum2[tid] * (1.f / 16384.f);
        float var  = ssqs2[tid] * (1.f / 16384.f) - mean * mean;
        float s    = gamma2[tid] * rsqrtf(var + 1e-5f);
        sc[tid] = s; sh[tid] = beta2[tid] - mean * s;
    }
    __syncthreads();

    // fused BN+ReLU+kernel-gen: 2b x 4kk x 16q = 128 tasks
    if (tid < 128) {
        int bb = tid >> 6, kk = (tid >> 4) & 3, q = tid & 15;
        const float* rp = rpre2 + (size_t)(b0 + bb) * 2048;
        float s = 0.f;
        #pragma unroll
        for (int o = 0; o < 128; ++o)
            s = fmaf(wspan2[kk * 128 + o],
                     fmaxf(fmaf(sc[o], rp[o * 16 + q], sh[o]), 0.f), s);
        kl[bb][kk][q] = s;
    }
    __syncthreads();

    #pragma unroll
    for (int bb = 0; bb < 2; ++bb) {
        const float* xb2 = xi2 + (size_t)(b0 + bb) * 128 * 64;
        for (int e = tid; e < 2048; e += 256) {
            int o = e >> 4, q = e & 15, ho = q >> 2, wo = q & 3;
            const float* p = xb2 + ((size_t)(o * 8 + 2 * ho)) * 8 + 2 * wo;
            float2 t  = *(const float2*)p;
            float2 bo = *(const float2*)(p + 8);
            Xl[bb][o][q] = kl[bb][0][q] * t.x + kl[bb][1][q] * t.y
                         + kl[bb][2][q] * bo.x + kl[bb][3][q] * bo.y;
        }
    }
    __syncthreads();

    const int tn = tid & 3, tm = tid >> 2;   // tm 0..63: rows tm*4..+3 of M-half
    for (int mh = 0; mh < 2; ++mh) {
        float acc[2][4][4];
        #pragma unroll
        for (int bb = 0; bb < 2; ++bb)
            #pragma unroll
            for (int i = 0; i < 4; ++i)
                #pragma unroll
                for (int j = 0; j < 4; ++j) acc[bb][i][j] = 0.f;

        for (int c0 = 0; c0 < 128; c0 += 32) {
            if (mh || c0) __syncthreads();   // protect Ws reuse
            for (int e4 = tid; e4 < 2048; e4 += 256) {
                int c = e4 >> 6, m4 = e4 & 63;
                ((float4*)Ws)[e4] = *(const float4*)(wT3 + (size_t)(c0 + c) * 512 + mh * 256 + m4 * 4);
            }
            __syncthreads();
            #pragma unroll
            for (int bb = 0; bb < 2; ++bb) {
                #pragma unroll
                for (int c = 0; c < 32; ++c) {
                    float4 xa = *(const float4*)(&Xl[bb][c0 + c][tn * 4]);
                    float4 wa = *(const float4*)(&Ws[c][tm * 4]);
                    float xfv[4] = {xa.x, xa.y, xa.z, xa.w};
                    float wf[4] = {wa.x, wa.y, wa.z, wa.w};
                    #pragma unroll
                    for (int i = 0; i < 4; ++i)
                        #pragma unroll
                        for (int j = 0; j < 4; ++j)
                            acc[bb][i][j] = fmaf(wf[i], xfv[j], acc[bb][i][j]);
                }
            }
        }
        #pragma unroll
        for (int bb = 0; bb < 2; ++bb) {
            const int b = b0 + bb;
            if (mh == 0) {    // xi3 rows tm*4+i
                #pragma unroll
                for (int i = 0; i < 4; ++i)
                    *(float4*)(xi3 + ((size_t)b * 256 + tm * 4 + i) * 16 + tn * 4) =
                        float4{acc[bb][i][0], acc[bb][i][1], acc[bb][i][2], acc[bb][i][3]};
            } else {          // red rows -> rpre3 + stats
                #pragma unroll
                for (int i = 0; i < 4; ++i) {
                    const int mr = tm * 4 + i;
                    *(float4*)(rpre3 + ((size_t)b * 256 + mr) * 16 + tn * 4) =
                        float4{acc[bb][i][0], acc[bb][i][1], acc[bb][i][2], acc[bb][i][3]};
                    float s1 = acc[bb][i][0] + acc[bb][i][1] + acc[bb][i][2] + acc[bb][i][3];
                    float s2 = acc[bb][i][0] * acc[bb][i][0] + acc[bb][i][1] * acc[bb][i][1]
                             + acc[bb][i][2] * acc[bb][i][2] + acc[bb][i][3] * acc[bb][i][3];
                    s1 += __shfl_xor(s1, 1); s2 += __shfl_xor(s2, 1);
                    s1 += __shfl_xor(s1, 2); s2 += __shfl_xor(s2, 2);
                    if (tn == 0) { atomicAdd(ssum3 + mr, s1); atomicAdd(ssqs3 + mr, s2); }
                }
            }
        }
    }
}

// ---------------- F4: p3(layer3, k=3,s=1,pad=1) fused with FC (R6 form) -------
__global__ __launch_bounds__(256) void f4_kernel(
    const float* __restrict__ xi3,    // [B][256][16]
    const float* __restrict__ rpre3,  // [B][256][16]
    const float* __restrict__ ssum3, const float* __restrict__ ssqs3,
    const float* __restrict__ gamma3, const float* __restrict__ beta3,
    const float* __restrict__ wspan3, // [9][256]
    const float* __restrict__ wfc,    // [16][4096]
    const float* __restrict__ bfc,    // [16]
    float* __restrict__ out)          // [B][16]
{
    __shared__ float sc[256], sh[256];
    __shared__ float kl[9 * 16];
    __shared__ float xil[4096];
    __shared__ float rh[4096];
    __shared__ float red[4][16];
    const int tid = threadIdx.x, b = blockIdx.x;

    {
        float mean = ssum3[tid] * (1.f / 16384.f);
        float var  = ssqs3[tid] * (1.f / 16384.f) - mean * mean;
        float s    = gamma3[tid] * rsqrtf(var + 1e-5f);
        sc[tid] = s; sh[tid] = beta3[tid] - mean * s;
    }
    const float* xb3 = xi3 + (size_t)b * 4096;
    for (int e = tid; e < 1024; e += 256)
        ((float4*)xil)[e] = ((const float4*)xb3)[e];
    __syncthreads();

    const float* rp3 = rpre3 + (size_t)b * 4096;
    for (int e = tid; e < 4096; e += 256) {
        int o = e >> 4;
        rh[e] = fmaxf(fmaf(sc[o], rp3[e], sh[o]), 0.f);
    }
    __syncthreads();
    if (tid < 144) {
        int kk = tid >> 4, q = tid & 15;
        float s = 0.f;
        #pragma unroll
        for (int o = 0; o < 256; ++o)
            s = fmaf(wspan3[kk * 256 + o], rh[(o << 4) + q], s);
        kl[tid] = s;
    }
    __syncthreads();
    for (int e = tid; e < 4096; e += 256) {
        int o = e >> 4, q = e & 15, ho = q >> 2, wo = q & 3;
        float v = 0.f;
        const float* xo = xil + (o << 4);
        #pragma unroll
        for (int ki = 0; ki < 3; ++ki) {
            int h = ho + ki - 1;
            if (h < 0 || h >= 4) continue;
            #pragma unroll
            for (int kj = 0; kj < 3; ++kj) {
                int w = wo + kj - 1;
                if (w < 0 || w >= 4) continue;
                v = fmaf(kl[(ki * 3 + kj) * 16 + q], xo[h * 4 + w], v);
            }
        }
        rh[e] = v;
    }
    __syncthreads();

    float acc[16];
    #pragma unroll
    for (int n = 0; n < 16; ++n) acc[n] = 0.f;
    for (int i = 0; i < 16; ++i) {
        int f = tid + i * 256;
        float hv = rh[f];
        #pragma unroll
        for (int n = 0; n < 16; ++n)
            acc[n] = fmaf(hv, wfc[n * 4096 + f], acc[n]);
    }
    #pragma unroll
    for (int n = 0; n < 16; ++n) {
        float v = acc[n];
        #pragma unroll
        for (int off = 1; off < 64; off <<= 1) v += __shfl_xor(v, off);
        acc[n] = v;
    }
    const int wave = tid >> 6, lane = tid & 63;
    if (lane == 0) {
        #pragma unroll
        for (int n = 0; n < 16; ++n) red[wave][n] = acc[n];
    }
    __syncthreads();
    if (tid < 16)
        out[(size_t)b * 16 + tid] =
            red[0][tid] + red[1][tid] + red[2][tid] + red[3][tid] + bfc[tid];
}

// ---------------- launch ----------------
extern "C" void kernel_launch(void* const* d_in, const int* in_sizes, int n_in,
                              void* d_out, int out_size, void* d_ws, size_t ws_size,
                              hipStream_t stream) {
    const float* x    = (const float*)d_in[0];
    const float* Wi1  = (const float*)d_in[1];
    const float* Wr1  = (const float*)d_in[2];
    const float* g1   = (const float*)d_in[3];
    const float* be1  = (const float*)d_in[4];
    const float* Wsp1 = (const float*)d_in[5];
    const float* Wi2  = (const float*)d_in[6];
    const float* Wr2  = (const float*)d_in[7];
    const float* g2   = (const float*)d_in[8];
    const float* be2  = (const float*)d_in[9];
    const float* Wsp2 = (const float*)d_in[10];
    const float* Wi3  = (const float*)d_in[11];
    const float* Wr3  = (const float*)d_in[12];
    const float* g3   = (const float*)d_in[13];
    const float* be3  = (const float*)d_in[14];
    const float* Wsp3 = (const float*)d_in[15];
    const float* Wfc  = (const float*)d_in[16];
    const float* bfc  = (const float*)d_in[17];
    float* out = (float*)d_out;
    float* ws  = (float*)d_ws;

    float* wcat2 = ws + OFF_WCAT2;
    float* wcat3 = ws + OFF_WCAT3;
    float* sum1 = ws + OFF_SUM1; float* sqs1 = ws + OFF_SQS1;
    float* sum2 = ws + OFF_SUM2; float* sqs2 = ws + OFF_SQS2;
    float* sum3 = ws + OFF_SUM3; float* sqs3 = ws + OFF_SQS3;
    float* xi1   = ws + OFF_XI1;
    float* rpre1 = ws + OFF_RPRE1;
    float* xi2   = ws + OFF_XI2;
    float* rpre2 = ws + OFF_RPRE2;
    float* xi3   = ws + OFF_XI1;     // layer-1 region dead after f2 (kernel boundary)
    float* rpre3 = ws + OFF_RPRE1;
    unsigned short* apkh = (unsigned short*)(ws + OFF_APKH);  // aliases xi2 (dead now)
    unsigned short* apkl = (unsigned short*)(ws + OFF_APKL);

    prep_all<<<424, 256, 0, stream>>>(Wi1, Wr1, Wi2, Wr2, Wi3, Wr3, ws);
    prep_apk<<<112, 256, 0, stream>>>(Wi1, Wr1, apkh, apkl);

    p1_l1_mfma<<<2048, 512, 0, stream>>>(x, apkh, apkl, xi1, rpre1, sum1, sqs1);

    f2_kernel<<<512, 256, 0, stream>>>(xi1, rpre1, sum1, sqs1, g1, be1, Wsp1,
                                       wcat2, xi2, rpre2, sum2, sqs2);

    f3_kernel<<<512, 256, 0, stream>>>(xi2, rpre2, sum2, sqs2, g2, be2, Wsp2,
                                       wcat3, xi3, rpre3, sum3, sqs3);

    f4_kernel<<<1024, 256, 0, stream>>>(xi3, rpre3, sum3, sqs3, g3, be3, Wsp3,
                                        Wfc, bfc, out);
}

// Round 7
// 544.441 us; speedup vs baseline: 1.5193x; 1.5193x over previous
//
#include <hip/hip_runtime.h>

// ======================================================================
// Involution net: 3 x (1x1 conv + dynamic-kernel apply w/ batch BN) + FC
// B=1024, fp32 reference.
//
// R10: R6 config (best known, 703us) + ONE change: 8-way sharded BN-stat
// atomics. Evidence: every heavy kernel's per-block lifetime is ~32-37us
// regardless of structure; p1 and f2 both slowed +52% exactly when their
// atomics-per-address doubled (R7/R9 splits). Theory: same-line atomic
// RMW serialization at one L2 slice is the floor. Fix: atomicAdd into
// stat[blockIdx&7][ch]; consumers sum 8 shards in the BN prologue.
// Shards live in the dead wcat1 region -> workspace footprint unchanged.
// All heavy-kernel bodies are the R6-benched versions verbatim.
// ======================================================================

typedef __attribute__((ext_vector_type(8))) short short8v;   // 8 bf16 bit-patterns
typedef __attribute__((ext_vector_type(4))) float f32x4;

__device__ __forceinline__ unsigned short f2bf_rne(float x) {
    unsigned u = __float_as_uint(x);
    unsigned r = u + 0x7FFFu + ((u >> 16) & 1u);
    return (unsigned short)(r >> 16);
}
__device__ __forceinline__ float bf2f(unsigned short h) {
    return __uint_as_float(((unsigned)h) << 16);
}

// sharded stats in [0, 7168) (dead wcat1 region)
static constexpr size_t OFF_SUM1  = 0;      // 8 x 64
static constexpr size_t OFF_SQS1  = 512;
static constexpr size_t OFF_SUM2  = 1024;   // 8 x 128
static constexpr size_t OFF_SQS2  = 2048;
static constexpr size_t OFF_SUM3  = 3072;   // 8 x 256
static constexpr size_t OFF_SQS3  = 5120;   // end 7168
static constexpr size_t OFF_WCAT2 = 25600;
static constexpr size_t OFF_WCAT3 = 41984;
static constexpr size_t OFF_XI1   = 108416;     // 16777216 floats (also xi3)
static constexpr size_t OFF_RPRE1 = 16885632;   //  4194304 floats (also rpre3)
static constexpr size_t OFF_XI2   = 21079936;   //  8388608 floats
static constexpr size_t OFF_RPRE2 = 29468544;   //  2097152 floats -> end 31565696
static constexpr size_t OFF_APKH  = OFF_XI2;            // aliases xi2 (dead then)
static constexpr size_t OFF_APKL  = OFF_XI2 + 14336;

// ---------------- prep: shard-stat zero + wcat2/3 concat-transpose ----------------
__global__ void prep_all(const float* __restrict__ wi2, const float* __restrict__ wr2,
                         const float* __restrict__ wi3, const float* __restrict__ wr3,
                         float* __restrict__ ws) {
    int e = blockIdx.x * 256 + threadIdx.x;
    if (e < 7168) { ws[e] = 0.f; return; }        // sharded BN stat accumulators
    if (e < 25600 || e >= 107520) return;
    const float* wi; const float* wr; float* wt; int cin, cout;
    if (e < 41984) { e -= 25600; wi = wi2; wr = wr2; wt = ws + OFF_WCAT2; cin = 64;  cout = 128; }
    else           { e -= 41984; wi = wi3; wr = wr3; wt = ws + OFF_WCAT3; cin = 128; cout = 256; }
    int M = 2 * cout, c = e / M, m = e % M;
    wt[e] = (m < cout) ? wi[m * cin + c] : wr[(m - cout) * cin + c];
}

// ---------------- A-fragment packing for p1_l1 MFMA ----------------
__global__ void prep_apk(const float* __restrict__ wi1, const float* __restrict__ wr1,
                         unsigned short* __restrict__ ah, unsigned short* __restrict__ al) {
    int e = blockIdx.x * 256 + threadIdx.x;
    if (e >= 28672) return;
    int v  = e & 7;
    int l  = (e >> 3) & 63;
    int mt = (e >> 9) & 7;
    int ck = e >> 12;
    int c = 32 * ck + ((l >> 4) << 3) + v;
    int m = 16 * mt + (l & 15);
    float wv = 0.f;
    if (c < 200) wv = (m < 64) ? wi1[m * 200 + c] : wr1[(m - 64) * 200 + c];
    unsigned short h = f2bf_rne(wv);
    ah[e] = h;
    al[e] = f2bf_rne(wv - bf2f(h));
}

// ---------------- P1 layer 1 via split-bf16 MFMA (R6-benched body) ----------------
// Per block (batch b): D[128][256] = Wcat[128][200] * x[b][200][256].
// 512 thr = 8 waves; wave w owns m-tile w; K padded to 224 = 7 chunks of 32.
__global__ __launch_bounds__(512) void p1_l1_mfma(
    const float* __restrict__ x,      // [B][200][256]
    const unsigned short* __restrict__ aHiG,
    const unsigned short* __restrict__ aLoG,
    float* __restrict__ xi,           // [B][64][256]
    float* __restrict__ rpre,         // [B][64][64]
    float* __restrict__ ssum, float* __restrict__ ssqs)   // 8x64 shards
{
    __shared__ __align__(16) unsigned short bHi[8192];  // [nt][lane][8]
    __shared__ __align__(16) unsigned short bLo[8192];
    const int tid = threadIdx.x, b = blockIdx.x;
    const int lane = tid & 63, w = tid >> 6;
    const int shard = (b & 7) * 64;
    const float* xb = x + (size_t)b * 200 * 256;

    f32x4 acc[16];
    #pragma unroll
    for (int i = 0; i < 16; ++i) acc[i] = f32x4{0.f, 0.f, 0.f, 0.f};

    float v0[8], v1[8];
    auto load_slot = [&](int s, int c0, float* v) {
        int l = s & 63;
        int n = (((s >> 6) << 4)) | (l & 15);
        int cb = c0 + ((l >> 4) << 3);
        #pragma unroll
        for (int j = 0; j < 8; ++j) {
            int c = cb + j;
            v[j] = (c < 200) ? xb[c * 256 + n] : 0.f;
        }
    };
    auto write_slot = [&](int s, const float* v) {
        unsigned short h[8], g[8];
        #pragma unroll
        for (int j = 0; j < 8; ++j) {
            h[j] = f2bf_rne(v[j]);
            g[j] = f2bf_rne(v[j] - bf2f(h[j]));
        }
        uint4 ph, pl;
        ph.x = (unsigned)h[0] | ((unsigned)h[1] << 16);
        ph.y = (unsigned)h[2] | ((unsigned)h[3] << 16);
        ph.z = (unsigned)h[4] | ((unsigned)h[5] << 16);
        ph.w = (unsigned)h[6] | ((unsigned)h[7] << 16);
        pl.x = (unsigned)g[0] | ((unsigned)g[1] << 16);
        pl.y = (unsigned)g[2] | ((unsigned)g[3] << 16);
        pl.z = (unsigned)g[4] | ((unsigned)g[5] << 16);
        pl.w = (unsigned)g[6] | ((unsigned)g[7] << 16);
        *(uint4*)(bHi + (size_t)s * 8) = ph;
        *(uint4*)(bLo + (size_t)s * 8) = pl;
    };

    load_slot(tid, 0, v0);
    load_slot(tid + 512, 0, v1);

    for (int ck = 0; ck < 7; ++ck) {
        write_slot(tid, v0);
        write_slot(tid + 512, v1);
        __syncthreads();
        if (ck < 6) {
            load_slot(tid, 32 * (ck + 1), v0);
            load_slot(tid + 512, 32 * (ck + 1), v1);
        }
        const size_t abase = ((size_t)(ck * 8 + w) * 64 + lane) * 8;
        short8v aH = *(const short8v*)(aHiG + abase);
        short8v aL = *(const short8v*)(aLoG + abase);
        #pragma unroll
        for (int nt = 0; nt < 16; ++nt) {
            short8v bH = *(const short8v*)(bHi + ((size_t)(nt * 64 + lane)) * 8);
            short8v bL = *(const short8v*)(bLo + ((size_t)(nt * 64 + lane)) * 8);
            acc[nt] = __builtin_amdgcn_mfma_f32_16x16x32_bf16(aH, bH, acc[nt], 0, 0, 0);
            acc[nt] = __builtin_amdgcn_mfma_f32_16x16x32_bf16(aH, bL, acc[nt], 0, 0, 0);
            acc[nt] = __builtin_amdgcn_mfma_f32_16x16x32_bf16(aL, bH, acc[nt], 0, 0, 0);
        }
        __syncthreads();
    }

    const int g = lane >> 4, col = lane & 15;
    if (w < 4) {
        float* xr = xi + ((size_t)b * 64 + 16 * w + 4 * g) * 256 + col;
        #pragma unroll
        for (int r = 0; r < 4; ++r)
            #pragma unroll
            for (int nt = 0; nt < 16; ++nt)
                xr[(size_t)r * 256 + nt * 16] = acc[nt][r];
    } else {
        #pragma unroll
        for (int r = 0; r < 4; ++r) {
            const int mr = 16 * (w - 4) + 4 * g + r;
            float pv[8], s1 = 0.f, s2 = 0.f;
            #pragma unroll
            for (int ph = 0; ph < 8; ++ph) {
                float a0 = acc[2 * ph][r], a1 = acc[2 * ph + 1][r];
                float p = 0.25f * (a0 + __shfl_xor(a0, 1) + a1 + __shfl_xor(a1, 1));
                pv[ph] = p; s1 += p; s2 += p * p;
            }
            if ((col & 1) == 0) {
                float* rp = rpre + ((size_t)b * 64 + mr) * 64 + (col >> 1);
                #pragma unroll
                for (int ph = 0; ph < 8; ++ph) rp[ph * 8] = pv[ph];
            }
            s1 += __shfl_xor(s1, 2); s2 += __shfl_xor(s2, 2);
            s1 += __shfl_xor(s1, 4); s2 += __shfl_xor(s2, 4);
            s1 += __shfl_xor(s1, 8); s2 += __shfl_xor(s2, 8);
            if (col == 0) { atomicAdd(ssum + shard + mr, s1); atomicAdd(ssqs + shard + mr, s2); }
        }
    }
}

// ---------------- F2: p3(layer1) fused with p1_l2 (R6-benched body) ----------------
__global__ __launch_bounds__(256) void f2_kernel(
    const float* __restrict__ xi1,    // [B][64][256]
    const float* __restrict__ rpre1,  // [B][64][64]
    const float* __restrict__ ssum1, const float* __restrict__ ssqs1,  // 8x64 shards
    const float* __restrict__ gamma1, const float* __restrict__ beta1,
    const float* __restrict__ wspan1, // [4][64]
    const float* __restrict__ wT2,    // [64][256]
    float* __restrict__ xi2,          // [B][128][64]
    float* __restrict__ rpre2,        // [B][128][16]
    float* __restrict__ ssum2, float* __restrict__ ssqs2)  // 8x128 shards
{
    __shared__ float sc[64], sh[64];
    __shared__ float kl[4 * 64];
    __shared__ float rws[4096];   // rl in phase A, Ws chunk (16x256) in phase B
    __shared__ float Xl[4096];    // out1[b] = [64][64]
    const int tid = threadIdx.x, b = blockIdx.x;
    const int shard = (b & 7) * 128;

    if (tid < 64) {
        float s1v = 0.f, s2v = 0.f;
        #pragma unroll
        for (int s = 0; s < 8; ++s) { s1v += ssum1[s * 64 + tid]; s2v += ssqs1[s * 64 + tid]; }
        float mean = s1v * (1.f / 65536.f);
        float var  = s2v * (1.f / 65536.f) - mean * mean;
        float s    = gamma1[tid] * rsqrtf(var + 1e-5f);
        sc[tid] = s; sh[tid] = beta1[tid] - mean * s;
    }
    __syncthreads();
    const float* rp1 = rpre1 + (size_t)b * 4096;
    for (int e = tid; e < 4096; e += 256) {
        int o = e >> 6;
        rws[e] = fmaxf(fmaf(sc[o], rp1[e], sh[o]), 0.f);
    }
    __syncthreads();
    {
        int kk = tid >> 6, q = tid & 63;
        float s = 0.f;
        #pragma unroll
        for (int o = 0; o < 64; ++o)
            s = fmaf(wspan1[kk * 64 + o], rws[(o << 6) + q], s);
        kl[tid] = s;
    }
    __syncthreads();
    const float* xb1 = xi1 + (size_t)b * 64 * 256;
    for (int e = tid; e < 4096; e += 256) {
        int o = e >> 6, q = e & 63, ho = q >> 3, wo = q & 7;
        const float* p = xb1 + ((size_t)(o * 16 + 2 * ho)) * 16 + 2 * wo;
        float2 t  = *(const float2*)p;
        float2 bo = *(const float2*)(p + 16);
        Xl[e] = kl[q] * t.x + kl[64 + q] * t.y + kl[128 + q] * bo.x + kl[192 + q] * bo.y;
    }
    __syncthreads();

    const int tn = tid & 7, tm = tid >> 3;
    float acc[8][8];
    #pragma unroll
    for (int i = 0; i < 8; ++i)
        #pragma unroll
        for (int j = 0; j < 8; ++j) acc[i][j] = 0.f;

    for (int c0 = 0; c0 < 64; c0 += 16) {
        for (int e = tid * 4; e < 4096; e += 1024)
            *(float4*)(rws + e) = *(const float4*)(wT2 + (size_t)c0 * 256 + e);
        __syncthreads();
        #pragma unroll
        for (int c = 0; c < 16; ++c) {
            float4 xa = *(const float4*)(Xl + (c0 + c) * 64 + tn * 4);
            float4 xc = *(const float4*)(Xl + (c0 + c) * 64 + 32 + tn * 4);
            float4 wa = *(const float4*)(rws + c * 256 + tm * 4);
            float4 wb = *(const float4*)(rws + c * 256 + 128 + tm * 4);
            float xf[8] = {xa.x, xa.y, xa.z, xa.w, xc.x, xc.y, xc.z, xc.w};
            float wf[8] = {wa.x, wa.y, wa.z, wa.w, wb.x, wb.y, wb.z, wb.w};
            #pragma unroll
            for (int i = 0; i < 8; ++i)
                #pragma unroll
                for (int j = 0; j < 8; ++j)
                    acc[i][j] = fmaf(wf[i], xf[j], acc[i][j]);
        }
        __syncthreads();
    }

    const int gr = tm * 4;
    #pragma unroll
    for (int i = 0; i < 4; ++i) {
        float* dst = xi2 + ((size_t)b * 128 + gr + i) * 64 + tn * 4;
        float4 v0 = {acc[i][0], acc[i][1], acc[i][2], acc[i][3]};
        float4 v1 = {acc[i][4], acc[i][5], acc[i][6], acc[i][7]};
        *(float4*)dst = v0;
        *(float4*)(dst + 32) = v1;
    }
    const bool val = (tn & 2) == 0;
    #pragma unroll
    for (int i = 4; i < 8; ++i) {
        const int mr = gr + i - 4;
        float hp0 = acc[i][0] + acc[i][1], hp1 = acc[i][2] + acc[i][3];
        float hp2 = acc[i][4] + acc[i][5], hp3 = acc[i][6] + acc[i][7];
        float p0 = 0.25f * (hp0 + __shfl_xor(hp0, 2));
        float p1 = 0.25f * (hp1 + __shfl_xor(hp1, 2));
        float p2 = 0.25f * (hp2 + __shfl_xor(hp2, 2));
        float p3 = 0.25f * (hp3 + __shfl_xor(hp3, 2));
        float s1 = val ? (p0 + p1 + p2 + p3) : 0.f;
        float s2 = val ? (p0 * p0 + p1 * p1 + p2 * p2 + p3 * p3) : 0.f;
        if (val) {
            const int wo = (tn & 1) * 2, ho = tn >> 2;
            float* rp = rpre2 + ((size_t)b * 128 + mr) * 16;
            *(float2*)(rp + ho * 4 + wo) = float2{p0, p1};
            *(float2*)(rp + (2 + ho) * 4 + wo) = float2{p2, p3};
        }
        #pragma unroll
        for (int off = 1; off <= 4; off <<= 1) {
            s1 += __shfl_xor(s1, off); s2 += __shfl_xor(s2, off);
        }
        if (tn == 0) { atomicAdd(ssum2 + shard + mr, s1); atomicAdd(ssqs2 + shard + mr, s2); }
    }
}

// ---------------- F3: p3(layer2) fused with p1_l3 (R6-benched body) ----------------
__global__ __launch_bounds__(256) void f3_kernel(
    const float* __restrict__ xi2,    // [B][128][64]
    const float* __restrict__ rpre2,  // [B][128][16]
    const float* __restrict__ ssum2, const float* __restrict__ ssqs2,  // 8x128 shards
    const float* __restrict__ gamma2, const float* __restrict__ beta2,
    const float* __restrict__ wspan2, // [4][128]
    const float* __restrict__ wT3,    // [128][512]
    float* __restrict__ xi3,          // [B][256][16]
    float* __restrict__ rpre3,        // [B][256][16]
    float* __restrict__ ssum3, float* __restrict__ ssqs3)  // 8x256 shards
{
    __shared__ float sc[128], sh[128];
    __shared__ float kl[4 * 16];
    __shared__ float rws[8192];
    __shared__ float Xl[2048];
    const int tid = threadIdx.x, b = blockIdx.x;
    const int shard = (b & 7) * 256;

    if (tid < 128) {
        float s1v = 0.f, s2v = 0.f;
        #pragma unroll
        for (int s = 0; s < 8; ++s) { s1v += ssum2[s * 128 + tid]; s2v += ssqs2[s * 128 + tid]; }
        float mean = s1v * (1.f / 16384.f);
        float var  = s2v * (1.f / 16384.f) - mean * mean;
        float s    = gamma2[tid] * rsqrtf(var + 1e-5f);
        sc[tid] = s; sh[tid] = beta2[tid] - mean * s;
    }
    __syncthreads();
    const float* rp2 = rpre2 + (size_t)b * 2048;
    for (int e = tid; e < 2048; e += 256) {
        int o = e >> 4;
        rws[e] = fmaxf(fmaf(sc[o], rp2[e], sh[o]), 0.f);
    }
    __syncthreads();
    if (tid < 64) {
        int kk = tid >> 4, q = tid & 15;
        float s = 0.f;
        #pragma unroll
        for (int o = 0; o < 128; ++o)
            s = fmaf(wspan2[kk * 128 + o], rws[(o << 4) + q], s);
        kl[tid] = s;
    }
    __syncthreads();
    const float* xb2 = xi2 + (size_t)b * 128 * 64;
    for (int e = tid; e < 2048; e += 256) {
        int o = e >> 4, q = e & 15, ho = q >> 2, wo = q & 3;
        const float* p = xb2 + ((size_t)(o * 8 + 2 * ho)) * 8 + 2 * wo;
        float2 t  = *(const float2*)p;
        float2 bo = *(const float2*)(p + 8);
        Xl[e] = kl[q] * t.x + kl[16 + q] * t.y + kl[32 + q] * bo.x + kl[48 + q] * bo.y;
    }
    __syncthreads();

    const int tn = tid & 3, tm = tid >> 2;
    float acc[8][4];
    #pragma unroll
    for (int i = 0; i < 8; ++i)
        #pragma unroll
        for (int j = 0; j < 4; ++j) acc[i][j] = 0.f;

    for (int c0 = 0; c0 < 128; c0 += 16) {
        for (int e = tid * 4; e < 8192; e += 1024)
            *(float4*)(rws + e) = *(const float4*)(wT3 + (size_t)c0 * 512 + e);
        __syncthreads();
        #pragma unroll
        for (int c = 0; c < 16; ++c) {
            float4 xa = *(const float4*)(Xl + (c0 + c) * 16 + tn * 4);
            float4 wa = *(const float4*)(rws + c * 512 + tm * 4);
            float4 wb = *(const float4*)(rws + c * 512 + 256 + tm * 4);
            float xfv[4] = {xa.x, xa.y, xa.z, xa.w};
            float wf[8] = {wa.x, wa.y, wa.z, wa.w, wb.x, wb.y, wb.z, wb.w};
            #pragma unroll
            for (int i = 0; i < 8; ++i)
                #pragma unroll
                for (int j = 0; j < 4; ++j)
                    acc[i][j] = fmaf(wf[i], xfv[j], acc[i][j]);
        }
        __syncthreads();
    }

    const int gr = tm * 4;
    #pragma unroll
    for (int i = 0; i < 4; ++i) {
        float4 v0 = {acc[i][0], acc[i][1], acc[i][2], acc[i][3]};
        *(float4*)(xi3 + ((size_t)b * 256 + gr + i) * 16 + tn * 4) = v0;
    }
    #pragma unroll
    for (int i = 4; i < 8; ++i) {
        const int mr = gr + i - 4;
        float4 v0 = {acc[i][0], acc[i][1], acc[i][2], acc[i][3]};
        *(float4*)(rpre3 + ((size_t)b * 256 + mr) * 16 + tn * 4) = v0;
        float s1 = acc[i][0] + acc[i][1] + acc[i][2] + acc[i][3];
        float s2 = acc[i][0] * acc[i][0] + acc[i][1] * acc[i][1]
                 + acc[i][2] * acc[i][2] + acc[i][3] * acc[i][3];
        s1 += __shfl_xor(s1, 1); s2 += __shfl_xor(s2, 1);
        s1 += __shfl_xor(s1, 2); s2 += __shfl_xor(s2, 2);
        if (tn == 0) { atomicAdd(ssum3 + shard + mr, s1); atomicAdd(ssqs3 + shard + mr, s2); }
    }
}

// ---------------- F4: p3(layer3, k=3,s=1,pad=1) fused with FC (R6 body) -------
__global__ __launch_bounds__(256) void f4_kernel(
    const float* __restrict__ xi3,    // [B][256][16]
    const float* __restrict__ rpre3,  // [B][256][16]
    const float* __restrict__ ssum3, const float* __restrict__ ssqs3,  // 8x256 shards
    const float* __restrict__ gamma3, const float* __restrict__ beta3,
    const float* __restrict__ wspan3, // [9][256]
    const float* __restrict__ wfc,    // [16][4096]
    const float* __restrict__ bfc,    // [16]
    float* __restrict__ out)          // [B][16]
{
    __shared__ float sc[256], sh[256];
    __shared__ float kl[9 * 16];
    __shared__ float xil[4096];
    __shared__ float rh[4096];
    __shared__ float red[4][16];
    const int tid = threadIdx.x, b = blockIdx.x;

    {
        float s1v = 0.f, s2v = 0.f;
        #pragma unroll
        for (int s = 0; s < 8; ++s) { s1v += ssum3[s * 256 + tid]; s2v += ssqs3[s * 256 + tid]; }
        float mean = s1v * (1.f / 16384.f);
        float var  = s2v * (1.f / 16384.f) - mean * mean;
        float s    = gamma3[tid] * rsqrtf(var + 1e-5f);
        sc[tid] = s; sh[tid] = beta3[tid] - mean * s;
    }
    const float* xb3 = xi3 + (size_t)b * 4096;
    for (int e = tid; e < 1024; e += 256)
        ((float4*)xil)[e] = ((const float4*)xb3)[e];
    __syncthreads();

    const float* rp3 = rpre3 + (size_t)b * 4096;
    for (int e = tid; e < 4096; e += 256) {
        int o = e >> 4;
        rh[e] = fmaxf(fmaf(sc[o], rp3[e], sh[o]), 0.f);
    }
    __syncthreads();
    if (tid < 144) {
        int kk = tid >> 4, q = tid & 15;
        float s = 0.f;
        #pragma unroll
        for (int o = 0; o < 256; ++o)
            s = fmaf(wspan3[kk * 256 + o], rh[(o << 4) + q], s);
        kl[tid] = s;
    }
    __syncthreads();
    for (int e = tid; e < 4096; e += 256) {
        int o = e >> 4, q = e & 15, ho = q >> 2, wo = q & 3;
        float v = 0.f;
        const float* xo = xil + (o << 4);
        #pragma unroll
        for (int ki = 0; ki < 3; ++ki) {
            int h = ho + ki - 1;
            if (h < 0 || h >= 4) continue;
            #pragma unroll
            for (int kj = 0; kj < 3; ++kj) {
                int w = wo + kj - 1;
                if (w < 0 || w >= 4) continue;
                v = fmaf(kl[(ki * 3 + kj) * 16 + q], xo[h * 4 + w], v);
            }
        }
        rh[e] = v;
    }
    __syncthreads();

    float acc[16];
    #pragma unroll
    for (int n = 0; n < 16; ++n) acc[n] = 0.f;
    for (int i = 0; i < 16; ++i) {
        int f = tid + i * 256;
        float hv = rh[f];
        #pragma unroll
        for (int n = 0; n < 16; ++n)
            acc[n] = fmaf(hv, wfc[n * 4096 + f], acc[n]);
    }
    #pragma unroll
    for (int n = 0; n < 16; ++n) {
        float v = acc[n];
        #pragma unroll
        for (int off = 1; off < 64; off <<= 1) v += __shfl_xor(v, off);
        acc[n] = v;
    }
    const int wave = tid >> 6, lane = tid & 63;
    if (lane == 0) {
        #pragma unroll
        for (int n = 0; n < 16; ++n) red[wave][n] = acc[n];
    }
    __syncthreads();
    if (tid < 16)
        out[(size_t)b * 16 + tid] =
            red[0][tid] + red[1][tid] + red[2][tid] + red[3][tid] + bfc[tid];
}

// ---------------- launch ----------------
extern "C" void kernel_launch(void* const* d_in, const int* in_sizes, int n_in,
                              void* d_out, int out_size, void* d_ws, size_t ws_size,
                              hipStream_t stream) {
    const float* x    = (const float*)d_in[0];
    const float* Wi1  = (const float*)d_in[1];
    const float* Wr1  = (const float*)d_in[2];
    const float* g1   = (const float*)d_in[3];
    const float* be1  = (const float*)d_in[4];
    const float* Wsp1 = (const float*)d_in[5];
    const float* Wi2  = (const float*)d_in[6];
    const float* Wr2  = (const float*)d_in[7];
    const float* g2   = (const float*)d_in[8];
    const float* be2  = (const float*)d_in[9];
    const float* Wsp2 = (const float*)d_in[10];
    const float* Wi3  = (const float*)d_in[11];
    const float* Wr3  = (const float*)d_in[12];
    const float* g3   = (const float*)d_in[13];
    const float* be3  = (const float*)d_in[14];
    const float* Wsp3 = (const float*)d_in[15];
    const float* Wfc  = (const float*)d_in[16];
    const float* bfc  = (const float*)d_in[17];
    float* out = (float*)d_out;
    float* ws  = (float*)d_ws;

    float* sum1 = ws + OFF_SUM1; float* sqs1 = ws + OFF_SQS1;
    float* sum2 = ws + OFF_SUM2; float* sqs2 = ws + OFF_SQS2;
    float* sum3 = ws + OFF_SUM3; float* sqs3 = ws + OFF_SQS3;
    float* wcat2 = ws + OFF_WCAT2;
    float* wcat3 = ws + OFF_WCAT3;
    float* xi1   = ws + OFF_XI1;
    float* rpre1 = ws + OFF_RPRE1;
    float* xi2   = ws + OFF_XI2;
    float* rpre2 = ws + OFF_RPRE2;
    float* xi3   = ws + OFF_XI1;     // layer-1 region dead after f2 (kernel boundary)
    float* rpre3 = ws + OFF_RPRE1;
    unsigned short* apkh = (unsigned short*)(ws + OFF_APKH);  // aliases xi2 (dead now)
    unsigned short* apkl = (unsigned short*)(ws + OFF_APKL);

    prep_all<<<420, 256, 0, stream>>>(Wi2, Wr2, Wi3, Wr3, ws);
    prep_apk<<<112, 256, 0, stream>>>(Wi1, Wr1, apkh, apkl);

    p1_l1_mfma<<<1024, 512, 0, stream>>>(x, apkh, apkl, xi1, rpre1, sum1, sqs1);

    f2_kernel<<<1024, 256, 0, stream>>>(xi1, rpre1, sum1, sqs1, g1, be1, Wsp1,
                                        wcat2, xi2, rpre2, sum2, sqs2);

    f3_kernel<<<1024, 256, 0, stream>>>(xi2, rpre2, sum2, sqs2, g2, be2, Wsp2,
                                        wcat3, xi3, rpre3, sum3, sqs3);

    f4_kernel<<<1024, 256, 0, stream>>>(xi3, rpre3, sum3, sqs3, g3, be3, Wsp3,
                                        Wfc, bfc, out);
}

// Round 8
// 468.870 us; speedup vs baseline: 1.7642x; 1.1612x over previous
//
#include <hip/hip_runtime.h>

// ======================================================================
// Involution net: 3 x (1x1 conv + dynamic-kernel apply w/ batch BN) + FC
// B=1024, fp32 reference.
//
// R11 = R10 (544us: sharded BN-stat atomics, confirmed -23%) + MFMA-ized
// f2/f3 phase-B GEMMs (split-bf16, same machinery as p1):
//  * prep_apk packs W2cat(256x64), W3cat(512x128) into per-lane MFMA
//    A-fragments hi/lo (wcat transpose prep removed).
//  * f2/f3: phase A unchanged; Xl stored PADDED ([64][65], [128][17]) so
//    the strided fragment gather is <=2-way bank-aliased (free, m136);
//    one conversion pass -> B-frags in LDS; 96 MFMA/wave replaces
//    2048 fma-inst/wave (~8x issue reduction).
//  * Epilogues on the HW-verified C/D map (col=lane&15, row=4g+r):
//    pool = shfl_xor(v,1), shfl_xor(hp,8); stats reduced in-group,
//    sharded atomics kept (b&7).
// p1/f4 are R10 bodies verbatim (failure isolation).
// ======================================================================

typedef __attribute__((ext_vector_type(8))) short short8v;   // 8 bf16 bit-patterns
typedef __attribute__((ext_vector_type(4))) float f32x4;

__device__ __forceinline__ unsigned short f2bf_rne(float x) {
    unsigned u = __float_as_uint(x);
    unsigned r = u + 0x7FFFu + ((u >> 16) & 1u);
    return (unsigned short)(r >> 16);
}
__device__ __forceinline__ float bf2f(unsigned short h) {
    return __uint_as_float(((unsigned)h) << 16);
}

// sharded stats in [0, 7168)
static constexpr size_t OFF_SUM1  = 0;      // 8 x 64
static constexpr size_t OFF_SQS1  = 512;
static constexpr size_t OFF_SUM2  = 1024;   // 8 x 128
static constexpr size_t OFF_SQS2  = 2048;
static constexpr size_t OFF_SUM3  = 3072;   // 8 x 256
static constexpr size_t OFF_SQS3  = 5120;   // end 7168
// packed A-fragments for f2/f3 (persistent, dead old-wcat region)
static constexpr size_t OFF_A2H   = 7168;   // 16384 ushort = 8192 floats
static constexpr size_t OFF_A2L   = 15360;
static constexpr size_t OFF_A3H   = 23552;  // 65536 ushort = 32768 floats
static constexpr size_t OFF_A3L   = 56320;  // end 89088 < 107520
static constexpr size_t OFF_XI1   = 108416;     // 16777216 floats (also xi3)
static constexpr size_t OFF_RPRE1 = 16885632;   //  4194304 floats (also rpre3)
static constexpr size_t OFF_XI2   = 21079936;   //  8388608 floats
static constexpr size_t OFF_RPRE2 = 29468544;   //  2097152 floats -> end 31565696
static constexpr size_t OFF_APKH  = OFF_XI2;            // p1 frags alias xi2 (dead then)
static constexpr size_t OFF_APKL  = OFF_XI2 + 14336;

// ---------------- prep: shard-stat zero ----------------
__global__ void prep_all(float* __restrict__ ws) {
    int e = blockIdx.x * 256 + threadIdx.x;
    if (e < 7168) ws[e] = 0.f;
}

// ---------------- A-fragment packing: p1 + f2 + f3 ----------------
// layout: frag[ck][mt][lane][v] = bf16 of Wcat[16*mt + (lane&15)][32*ck + 8*(lane>>4) + v]
__global__ void prep_apk(const float* __restrict__ wi1, const float* __restrict__ wr1,
                         const float* __restrict__ wi2, const float* __restrict__ wr2,
                         const float* __restrict__ wi3, const float* __restrict__ wr3,
                         unsigned short* __restrict__ a1h, unsigned short* __restrict__ a1l,
                         unsigned short* __restrict__ a2h, unsigned short* __restrict__ a2l,
                         unsigned short* __restrict__ a3h, unsigned short* __restrict__ a3l) {
    int e = blockIdx.x * 256 + threadIdx.x;
    if (e >= 110592) return;
    float wv; unsigned short* dh; unsigned short* dl; int idx;
    if (e < 28672) {                 // p1: M=128, K=200 pad 224 (7 ck), 8 mt
        int v = e & 7, l = (e >> 3) & 63, mt = (e >> 9) & 7, ck = e >> 12;
        int c = 32 * ck + ((l >> 4) << 3) + v;
        int m = 16 * mt + (l & 15);
        wv = 0.f;
        if (c < 200) wv = (m < 64) ? wi1[m * 200 + c] : wr1[(m - 64) * 200 + c];
        dh = a1h; dl = a1l; idx = e;
    } else if (e < 45056) {          // f2: M=256, K=64 (2 ck), 16 mt
        int e2 = e - 28672;
        int v = e2 & 7, l = (e2 >> 3) & 63, mt = (e2 >> 9) & 15, ck = e2 >> 13;
        int c = 32 * ck + ((l >> 4) << 3) + v;
        int m = 16 * mt + (l & 15);
        wv = (m < 128) ? wi2[m * 64 + c] : wr2[(m - 128) * 64 + c];
        dh = a2h; dl = a2l; idx = e2;
    } else {                         // f3: M=512, K=128 (4 ck), 32 mt
        int e3 = e - 45056;
        int v = e3 & 7, l = (e3 >> 3) & 63, mt = (e3 >> 9) & 31, ck = e3 >> 14;
        int c = 32 * ck + ((l >> 4) << 3) + v;
        int m = 16 * mt + (l & 15);
        wv = (m < 256) ? wi3[m * 128 + c] : wr3[(m - 256) * 128 + c];
        dh = a3h; dl = a3l; idx = e3;
    }
    unsigned short h = f2bf_rne(wv);
    dh[idx] = h;
    dl[idx] = f2bf_rne(wv - bf2f(h));
}

// ---------------- P1 layer 1 via split-bf16 MFMA (R10 body verbatim) ----------------
__global__ __launch_bounds__(512) void p1_l1_mfma(
    const float* __restrict__ x,      // [B][200][256]
    const unsigned short* __restrict__ aHiG,
    const unsigned short* __restrict__ aLoG,
    float* __restrict__ xi,           // [B][64][256]
    float* __restrict__ rpre,         // [B][64][64]
    float* __restrict__ ssum, float* __restrict__ ssqs)   // 8x64 shards
{
    __shared__ __align__(16) unsigned short bHi[8192];  // [nt][lane][8]
    __shared__ __align__(16) unsigned short bLo[8192];
    const int tid = threadIdx.x, b = blockIdx.x;
    const int lane = tid & 63, w = tid >> 6;
    const int shard = (b & 7) * 64;
    const float* xb = x + (size_t)b * 200 * 256;

    f32x4 acc[16];
    #pragma unroll
    for (int i = 0; i < 16; ++i) acc[i] = f32x4{0.f, 0.f, 0.f, 0.f};

    float v0[8], v1[8];
    auto load_slot = [&](int s, int c0, float* v) {
        int l = s & 63;
        int n = (((s >> 6) << 4)) | (l & 15);
        int cb = c0 + ((l >> 4) << 3);
        #pragma unroll
        for (int j = 0; j < 8; ++j) {
            int c = cb + j;
            v[j] = (c < 200) ? xb[c * 256 + n] : 0.f;
        }
    };
    auto write_slot = [&](int s, const float* v) {
        unsigned short h[8], g[8];
        #pragma unroll
        for (int j = 0; j < 8; ++j) {
            h[j] = f2bf_rne(v[j]);
            g[j] = f2bf_rne(v[j] - bf2f(h[j]));
        }
        uint4 ph, pl;
        ph.x = (unsigned)h[0] | ((unsigned)h[1] << 16);
        ph.y = (unsigned)h[2] | ((unsigned)h[3] << 16);
        ph.z = (unsigned)h[4] | ((unsigned)h[5] << 16);
        ph.w = (unsigned)h[6] | ((unsigned)h[7] << 16);
        pl.x = (unsigned)g[0] | ((unsigned)g[1] << 16);
        pl.y = (unsigned)g[2] | ((unsigned)g[3] << 16);
        pl.z = (unsigned)g[4] | ((unsigned)g[5] << 16);
        pl.w = (unsigned)g[6] | ((unsigned)g[7] << 16);
        *(uint4*)(bHi + (size_t)s * 8) = ph;
        *(uint4*)(bLo + (size_t)s * 8) = pl;
    };

    load_slot(tid, 0, v0);
    load_slot(tid + 512, 0, v1);

    for (int ck = 0; ck < 7; ++ck) {
        write_slot(tid, v0);
        write_slot(tid + 512, v1);
        __syncthreads();
        if (ck < 6) {
            load_slot(tid, 32 * (ck + 1), v0);
            load_slot(tid + 512, 32 * (ck + 1), v1);
        }
        const size_t abase = ((size_t)(ck * 8 + w) * 64 + lane) * 8;
        short8v aH = *(const short8v*)(aHiG + abase);
        short8v aL = *(const short8v*)(aLoG + abase);
        #pragma unroll
        for (int nt = 0; nt < 16; ++nt) {
            short8v bH = *(const short8v*)(bHi + ((size_t)(nt * 64 + lane)) * 8);
            short8v bL = *(const short8v*)(bLo + ((size_t)(nt * 64 + lane)) * 8);
            acc[nt] = __builtin_amdgcn_mfma_f32_16x16x32_bf16(aH, bH, acc[nt], 0, 0, 0);
            acc[nt] = __builtin_amdgcn_mfma_f32_16x16x32_bf16(aH, bL, acc[nt], 0, 0, 0);
            acc[nt] = __builtin_amdgcn_mfma_f32_16x16x32_bf16(aL, bH, acc[nt], 0, 0, 0);
        }
        __syncthreads();
    }

    const int g = lane >> 4, col = lane & 15;
    if (w < 4) {
        float* xr = xi + ((size_t)b * 64 + 16 * w + 4 * g) * 256 + col;
        #pragma unroll
        for (int r = 0; r < 4; ++r)
            #pragma unroll
            for (int nt = 0; nt < 16; ++nt)
                xr[(size_t)r * 256 + nt * 16] = acc[nt][r];
    } else {
        #pragma unroll
        for (int r = 0; r < 4; ++r) {
            const int mr = 16 * (w - 4) + 4 * g + r;
            float pv[8], s1 = 0.f, s2 = 0.f;
            #pragma unroll
            for (int ph = 0; ph < 8; ++ph) {
                float a0 = acc[2 * ph][r], a1 = acc[2 * ph + 1][r];
                float p = 0.25f * (a0 + __shfl_xor(a0, 1) + a1 + __shfl_xor(a1, 1));
                pv[ph] = p; s1 += p; s2 += p * p;
            }
            if ((col & 1) == 0) {
                float* rp = rpre + ((size_t)b * 64 + mr) * 64 + (col >> 1);
                #pragma unroll
                for (int ph = 0; ph < 8; ++ph) rp[ph * 8] = pv[ph];
            }
            s1 += __shfl_xor(s1, 2); s2 += __shfl_xor(s2, 2);
            s1 += __shfl_xor(s1, 4); s2 += __shfl_xor(s2, 4);
            s1 += __shfl_xor(s1, 8); s2 += __shfl_xor(s2, 8);
            if (col == 0) { atomicAdd(ssum + shard + mr, s1); atomicAdd(ssqs + shard + mr, s2); }
        }
    }
}

// ---------------- F2: p3(layer1) + p1_l2 with MFMA phase B ----------------
// Phase A as R10. Phase B: M=256 (128 xi + 128 red), N=64 (4 nt), K=64 (2 ck).
// 4 waves; wave w owns mt {w, w+4, w+8, w+12}; mi 0,1 = xi tiles, mi 2,3 = red.
__global__ __launch_bounds__(256) void f2_kernel(
    const float* __restrict__ xi1,    // [B][64][256]
    const float* __restrict__ rpre1,  // [B][64][64]
    const float* __restrict__ ssum1, const float* __restrict__ ssqs1,  // 8x64
    const float* __restrict__ gamma1, const float* __restrict__ beta1,
    const float* __restrict__ wspan1, // [4][64]
    const unsigned short* __restrict__ a2h, const unsigned short* __restrict__ a2l,
    float* __restrict__ xi2,          // [B][128][64]
    float* __restrict__ rpre2,        // [B][128][16]
    float* __restrict__ ssum2, float* __restrict__ ssqs2)  // 8x128
{
    __shared__ float sc[64], sh[64];
    __shared__ float kl[256];
    __shared__ float rl[4096];
    __shared__ float Xl[64 * 65];     // padded: gather is 2-way bank-aliased (free)
    __shared__ __align__(16) unsigned short bH[4096];  // [ck][nt*64+l][8]
    __shared__ __align__(16) unsigned short bL[4096];
    const int tid = threadIdx.x, b = blockIdx.x;
    const int shard = (b & 7) * 128;

    if (tid < 64) {
        float s1v = 0.f, s2v = 0.f;
        #pragma unroll
        for (int s = 0; s < 8; ++s) { s1v += ssum1[s * 64 + tid]; s2v += ssqs1[s * 64 + tid]; }
        float mean = s1v * (1.f / 65536.f);
        float var  = s2v * (1.f / 65536.f) - mean * mean;
        float s    = gamma1[tid] * rsqrtf(var + 1e-5f);
        sc[tid] = s; sh[tid] = beta1[tid] - mean * s;
    }
    __syncthreads();
    const float* rp1 = rpre1 + (size_t)b * 4096;
    for (int e = tid; e < 4096; e += 256) {
        int o = e >> 6;
        rl[e] = fmaxf(fmaf(sc[o], rp1[e], sh[o]), 0.f);
    }
    __syncthreads();
    {   // kgen: 4 kk x 64 q
        int kk = tid >> 6, q = tid & 63;
        float s = 0.f;
        #pragma unroll
        for (int o = 0; o < 64; ++o)
            s = fmaf(wspan1[kk * 64 + o], rl[(o << 6) + q], s);
        kl[tid] = s;
    }
    __syncthreads();
    const float* xb1 = xi1 + (size_t)b * 64 * 256;
    for (int e = tid; e < 4096; e += 256) {
        int o = e >> 6, q = e & 63, ho = q >> 3, wo = q & 7;
        const float* p = xb1 + ((size_t)(o * 16 + 2 * ho)) * 16 + 2 * wo;
        float2 t  = *(const float2*)p;
        float2 bo = *(const float2*)(p + 16);
        Xl[o * 65 + q] = kl[q] * t.x + kl[64 + q] * t.y + kl[128 + q] * bo.x + kl[192 + q] * bo.y;
    }
    __syncthreads();

    // B-fragment conversion: 512 slots (ck,nt,l), 2 per thread
    #pragma unroll
    for (int t = 0; t < 2; ++t) {
        int s = tid + t * 256;
        int ck = s >> 8, nt = (s >> 6) & 3, l = s & 63;
        int ob = ck * 32 + ((l >> 4) << 3), q = nt * 16 + (l & 15);
        unsigned short h[8], g8[8];
        #pragma unroll
        for (int j = 0; j < 8; ++j) {
            float v = Xl[(ob + j) * 65 + q];
            h[j] = f2bf_rne(v);
            g8[j] = f2bf_rne(v - bf2f(h[j]));
        }
        uint4 ph, pl;
        ph.x = (unsigned)h[0] | ((unsigned)h[1] << 16);
        ph.y = (unsigned)h[2] | ((unsigned)h[3] << 16);
        ph.z = (unsigned)h[4] | ((unsigned)h[5] << 16);
        ph.w = (unsigned)h[6] | ((unsigned)h[7] << 16);
        pl.x = (unsigned)g8[0] | ((unsigned)g8[1] << 16);
        pl.y = (unsigned)g8[2] | ((unsigned)g8[3] << 16);
        pl.z = (unsigned)g8[4] | ((unsigned)g8[5] << 16);
        pl.w = (unsigned)g8[6] | ((unsigned)g8[7] << 16);
        *(uint4*)(bH + ((size_t)ck * 2048 + (size_t)(nt * 64 + l) * 8)) = ph;
        *(uint4*)(bL + ((size_t)ck * 2048 + (size_t)(nt * 64 + l) * 8)) = pl;
    }
    __syncthreads();

    // MFMA phase B
    const int w = tid >> 6, l = tid & 63;
    f32x4 acc[4][4];
    #pragma unroll
    for (int i = 0; i < 4; ++i)
        #pragma unroll
        for (int j = 0; j < 4; ++j) acc[i][j] = f32x4{0.f, 0.f, 0.f, 0.f};
    #pragma unroll
    for (int ck = 0; ck < 2; ++ck) {
        #pragma unroll
        for (int mi = 0; mi < 4; ++mi) {
            int mt = w + 4 * mi;
            const size_t ab = ((size_t)(ck * 16 + mt) * 64 + l) * 8;
            short8v aH = *(const short8v*)(a2h + ab);
            short8v aL = *(const short8v*)(a2l + ab);
            #pragma unroll
            for (int nt = 0; nt < 4; ++nt) {
                short8v bHv = *(const short8v*)(bH + ((size_t)ck * 2048 + (size_t)(nt * 64 + l) * 8));
                short8v bLv = *(const short8v*)(bL + ((size_t)ck * 2048 + (size_t)(nt * 64 + l) * 8));
                acc[mi][nt] = __builtin_amdgcn_mfma_f32_16x16x32_bf16(aH, bHv, acc[mi][nt], 0, 0, 0);
                acc[mi][nt] = __builtin_amdgcn_mfma_f32_16x16x32_bf16(aH, bLv, acc[mi][nt], 0, 0, 0);
                acc[mi][nt] = __builtin_amdgcn_mfma_f32_16x16x32_bf16(aL, bHv, acc[mi][nt], 0, 0, 0);
            }
        }
    }

    // epilogue: C/D col = l&15 (q within nt), row = mt*16 + 4*(l>>4) + r
    const int g = l >> 4, c = l & 15;
    #pragma unroll
    for (int mi = 0; mi < 2; ++mi) {            // xi tiles (mt = w+4mi < 8)
        int mt = w + 4 * mi;
        #pragma unroll
        for (int r = 0; r < 4; ++r) {
            float* dst = xi2 + ((size_t)b * 128 + mt * 16 + 4 * g + r) * 64 + c;
            #pragma unroll
            for (int nt = 0; nt < 4; ++nt) dst[nt * 16] = acc[mi][nt][r];
        }
    }
    const bool valid = ((c & 1) == 0) && ((c & 8) == 0);
    #pragma unroll
    for (int mi = 2; mi < 4; ++mi) {            // red tiles (mt-8 in 0..7)
        int mt = w + 4 * mi - 8;
        #pragma unroll
        for (int r = 0; r < 4; ++r) {
            const int mr = mt * 16 + 4 * g + r;
            float pv[4], s1 = 0.f, s2 = 0.f;
            #pragma unroll
            for (int nt = 0; nt < 4; ++nt) {
                float v = acc[mi][nt][r];
                float hp = v + __shfl_xor(v, 1);      // q, q+1
                float p = 0.25f * (hp + __shfl_xor(hp, 8));  // + q+8, q+9
                pv[nt] = p; s1 += p; s2 += p * p;
            }
            if (valid) {
                float* rp = rpre2 + ((size_t)b * 128 + mr) * 16 + (c >> 1);
                #pragma unroll
                for (int nt = 0; nt < 4; ++nt) rp[nt * 4] = pv[nt];
            }
            s1 = valid ? s1 : 0.f; s2 = valid ? s2 : 0.f;
            #pragma unroll
            for (int off = 1; off <= 8; off <<= 1) {
                s1 += __shfl_xor(s1, off); s2 += __shfl_xor(s2, off);
            }
            if (c == 0) { atomicAdd(ssum2 + shard + mr, s1); atomicAdd(ssqs2 + shard + mr, s2); }
        }
    }
}

// ---------------- F3: p3(layer2) + p1_l3 with MFMA phase B ----------------
// Phase A as R10. Phase B: M=512 (256 xi + 256 red), N=16 (1 nt), K=128 (4 ck).
// 4 waves; wave w owns mt {w, w+4, ..., w+28}; mi 0-3 xi, mi 4-7 red.
__global__ __launch_bounds__(256) void f3_kernel(
    const float* __restrict__ xi2,    // [B][128][64]
    const float* __restrict__ rpre2,  // [B][128][16]
    const float* __restrict__ ssum2, const float* __restrict__ ssqs2,  // 8x128
    const float* __restrict__ gamma2, const float* __restrict__ beta2,
    const float* __restrict__ wspan2, // [4][128]
    const unsigned short* __restrict__ a3h, const unsigned short* __restrict__ a3l,
    float* __restrict__ xi3,          // [B][256][16]
    float* __restrict__ rpre3,        // [B][256][16]
    float* __restrict__ ssum3, float* __restrict__ ssqs3)  // 8x256
{
    __shared__ float sc[128], sh[128];
    __shared__ float kl[64];
    __shared__ float rl[2048];
    __shared__ float Xl[128 * 17];    // padded
    __shared__ __align__(16) unsigned short bH[2048];  // [ck][l][8]
    __shared__ __align__(16) unsigned short bL[2048];
    const int tid = threadIdx.x, b = blockIdx.x;
    const int shard = (b & 7) * 256;

    if (tid < 128) {
        float s1v = 0.f, s2v = 0.f;
        #pragma unroll
        for (int s = 0; s < 8; ++s) { s1v += ssum2[s * 128 + tid]; s2v += ssqs2[s * 128 + tid]; }
        float mean = s1v * (1.f / 16384.f);
        float var  = s2v * (1.f / 16384.f) - mean * mean;
        float s    = gamma2[tid] * rsqrtf(var + 1e-5f);
        sc[tid] = s; sh[tid] = beta2[tid] - mean * s;
    }
    __syncthreads();
    const float* rp2 = rpre2 + (size_t)b * 2048;
    for (int e = tid; e < 2048; e += 256) {
        int o = e >> 4;
        rl[e] = fmaxf(fmaf(sc[o], rp2[e], sh[o]), 0.f);
    }
    __syncthreads();
    if (tid < 64) {
        int kk = tid >> 4, q = tid & 15;
        float s = 0.f;
        #pragma unroll
        for (int o = 0; o < 128; ++o)
            s = fmaf(wspan2[kk * 128 + o], rl[(o << 4) + q], s);
        kl[tid] = s;
    }
    __syncthreads();
    const float* xb2 = xi2 + (size_t)b * 128 * 64;
    for (int e = tid; e < 2048; e += 256) {
        int o = e >> 4, q = e & 15, ho = q >> 2, wo = q & 3;
        const float* p = xb2 + ((size_t)(o * 8 + 2 * ho)) * 8 + 2 * wo;
        float2 t  = *(const float2*)p;
        float2 bo = *(const float2*)(p + 8);
        Xl[o * 17 + q] = kl[q] * t.x + kl[16 + q] * t.y + kl[32 + q] * bo.x + kl[48 + q] * bo.y;
    }
    __syncthreads();

    // B-fragment conversion: 4 ck x 64 slots = 256 = 1/thread
    {
        int ck = tid >> 6, l = tid & 63;
        int ob = ck * 32 + ((l >> 4) << 3), q = l & 15;
        unsigned short h[8], g8[8];
        #pragma unroll
        for (int j = 0; j < 8; ++j) {
            float v = Xl[(ob + j) * 17 + q];
            h[j] = f2bf_rne(v);
            g8[j] = f2bf_rne(v - bf2f(h[j]));
        }
        uint4 ph, pl;
        ph.x = (unsigned)h[0] | ((unsigned)h[1] << 16);
        ph.y = (unsigned)h[2] | ((unsigned)h[3] << 16);
        ph.z = (unsigned)h[4] | ((unsigned)h[5] << 16);
        ph.w = (unsigned)h[6] | ((unsigned)h[7] << 16);
        pl.x = (unsigned)g8[0] | ((unsigned)g8[1] << 16);
        pl.y = (unsigned)g8[2] | ((unsigned)g8[3] << 16);
        pl.z = (unsigned)g8[4] | ((unsigned)g8[5] << 16);
        pl.w = (unsigned)g8[6] | ((unsigned)g8[7] << 16);
        *(uint4*)(bH + (size_t)tid * 8) = ph;
        *(uint4*)(bL + (size_t)tid * 8) = pl;
    }
    __syncthreads();

    const int w = tid >> 6, l = tid & 63;
    f32x4 acc[8];
    #pragma unroll
    for (int i = 0; i < 8; ++i) acc[i] = f32x4{0.f, 0.f, 0.f, 0.f};
    #pragma unroll
    for (int ck = 0; ck < 4; ++ck) {
        short8v bHv = *(const short8v*)(bH + ((size_t)(ck * 64 + l)) * 8);
        short8v bLv = *(const short8v*)(bL + ((size_t)(ck * 64 + l)) * 8);
        #pragma unroll
        for (int mi = 0; mi < 8; ++mi) {
            int mt = w + 4 * mi;
            const size_t ab = ((size_t)(ck * 32 + mt) * 64 + l) * 8;
            short8v aH = *(const short8v*)(a3h + ab);
            short8v aL = *(const short8v*)(a3l + ab);
            acc[mi] = __builtin_amdgcn_mfma_f32_16x16x32_bf16(aH, bHv, acc[mi], 0, 0, 0);
            acc[mi] = __builtin_amdgcn_mfma_f32_16x16x32_bf16(aH, bLv, acc[mi], 0, 0, 0);
            acc[mi] = __builtin_amdgcn_mfma_f32_16x16x32_bf16(aL, bHv, acc[mi], 0, 0, 0);
        }
    }

    const int g = l >> 4, c = l & 15;
    #pragma unroll
    for (int mi = 0; mi < 4; ++mi) {            // xi tiles (mt < 16)
        int mt = w + 4 * mi;
        #pragma unroll
        for (int r = 0; r < 4; ++r)
            xi3[((size_t)b * 256 + mt * 16 + 4 * g + r) * 16 + c] = acc[mi][r];
    }
    #pragma unroll
    for (int mi = 4; mi < 8; ++mi) {            // red tiles
        int mt = w + 4 * mi - 16;
        #pragma unroll
        for (int r = 0; r < 4; ++r) {
            const int mr = mt * 16 + 4 * g + r;
            float v = acc[mi][r];
            rpre3[((size_t)b * 256 + mr) * 16 + c] = v;
            float s1 = v, s2 = v * v;
            #pragma unroll
            for (int off = 1; off <= 8; off <<= 1) {
                s1 += __shfl_xor(s1, off); s2 += __shfl_xor(s2, off);
            }
            if (c == 0) { atomicAdd(ssum3 + shard + mr, s1); atomicAdd(ssqs3 + shard + mr, s2); }
        }
    }
}

// ---------------- F4: p3(layer3) + FC (R10 body verbatim) ----------------
__global__ __launch_bounds__(256) void f4_kernel(
    const float* __restrict__ xi3,    // [B][256][16]
    const float* __restrict__ rpre3,  // [B][256][16]
    const float* __restrict__ ssum3, const float* __restrict__ ssqs3,  // 8x256
    const float* __restrict__ gamma3, const float* __restrict__ beta3,
    const float* __restrict__ wspan3, // [9][256]
    const float* __restrict__ wfc,    // [16][4096]
    const float* __restrict__ bfc,    // [16]
    float* __restrict__ out)          // [B][16]
{
    __shared__ float sc[256], sh[256];
    __shared__ float kl[9 * 16];
    __shared__ float xil[4096];
    __shared__ float rh[4096];
    __shared__ float red[4][16];
    const int tid = threadIdx.x, b = blockIdx.x;

    {
        float s1v = 0.f, s2v = 0.f;
        #pragma unroll
        for (int s = 0; s < 8; ++s) { s1v += ssum3[s * 256 + tid]; s2v += ssqs3[s * 256 + tid]; }
        float mean = s1v * (1.f / 16384.f);
        float var  = s2v * (1.f / 16384.f) - mean * mean;
        float s    = gamma3[tid] * rsqrtf(var + 1e-5f);
        sc[tid] = s; sh[tid] = beta3[tid] - mean * s;
    }
    const float* xb3 = xi3 + (size_t)b * 4096;
    for (int e = tid; e < 1024; e += 256)
        ((float4*)xil)[e] = ((const float4*)xb3)[e];
    __syncthreads();

    const float* rp3 = rpre3 + (size_t)b * 4096;
    for (int e = tid; e < 4096; e += 256) {
        int o = e >> 4;
        rh[e] = fmaxf(fmaf(sc[o], rp3[e], sh[o]), 0.f);
    }
    __syncthreads();
    if (tid < 144) {
        int kk = tid >> 4, q = tid & 15;
        float s = 0.f;
        #pragma unroll
        for (int o = 0; o < 256; ++o)
            s = fmaf(wspan3[kk * 256 + o], rh[(o << 4) + q], s);
        kl[tid] = s;
    }
    __syncthreads();
    for (int e = tid; e < 4096; e += 256) {
        int o = e >> 4, q = e & 15, ho = q >> 2, wo = q & 3;
        float v = 0.f;
        const float* xo = xil + (o << 4);
        #pragma unroll
        for (int ki = 0; ki < 3; ++ki) {
            int h = ho + ki - 1;
            if (h < 0 || h >= 4) continue;
            #pragma unroll
            for (int kj = 0; kj < 3; ++kj) {
                int w = wo + kj - 1;
                if (w < 0 || w >= 4) continue;
                v = fmaf(kl[(ki * 3 + kj) * 16 + q], xo[h * 4 + w], v);
            }
        }
        rh[e] = v;
    }
    __syncthreads();

    float acc[16];
    #pragma unroll
    for (int n = 0; n < 16; ++n) acc[n] = 0.f;
    for (int i = 0; i < 16; ++i) {
        int f = tid + i * 256;
        float hv = rh[f];
        #pragma unroll
        for (int n = 0; n < 16; ++n)
            acc[n] = fmaf(hv, wfc[n * 4096 + f], acc[n]);
    }
    #pragma unroll
    for (int n = 0; n < 16; ++n) {
        float v = acc[n];
        #pragma unroll
        for (int off = 1; off < 64; off <<= 1) v += __shfl_xor(v, off);
        acc[n] = v;
    }
    const int wave = tid >> 6, lane = tid & 63;
    if (lane == 0) {
        #pragma unroll
        for (int n = 0; n < 16; ++n) red[wave][n] = acc[n];
    }
    __syncthreads();
    if (tid < 16)
        out[(size_t)b * 16 + tid] =
            red[0][tid] + red[1][tid] + red[2][tid] + red[3][tid] + bfc[tid];
}

// ---------------- launch ----------------
extern "C" void kernel_launch(void* const* d_in, const int* in_sizes, int n_in,
                              void* d_out, int out_size, void* d_ws, size_t ws_size,
                              hipStream_t stream) {
    const float* x    = (const float*)d_in[0];
    const float* Wi1  = (const float*)d_in[1];
    const float* Wr1  = (const float*)d_in[2];
    const float* g1   = (const float*)d_in[3];
    const float* be1  = (const float*)d_in[4];
    const float* Wsp1 = (const float*)d_in[5];
    const float* Wi2  = (const float*)d_in[6];
    const float* Wr2  = (const float*)d_in[7];
    const float* g2   = (const float*)d_in[8];
    const float* be2  = (const float*)d_in[9];
    const float* Wsp2 = (const float*)d_in[10];
    const float* Wi3  = (const float*)d_in[11];
    const float* Wr3  = (const float*)d_in[12];
    const float* g3   = (const float*)d_in[13];
    const float* be3  = (const float*)d_in[14];
    const float* Wsp3 = (const float*)d_in[15];
    const float* Wfc  = (const float*)d_in[16];
    const float* bfc  = (const float*)d_in[17];
    float* out = (float*)d_out;
    float* ws  = (float*)d_ws;

    float* sum1 = ws + OFF_SUM1; float* sqs1 = ws + OFF_SQS1;
    float* sum2 = ws + OFF_SUM2; float* sqs2 = ws + OFF_SQS2;
    float* sum3 = ws + OFF_SUM3; float* sqs3 = ws + OFF_SQS3;
    float* xi1   = ws + OFF_XI1;
    float* rpre1 = ws + OFF_RPRE1;
    float* xi2   = ws + OFF_XI2;
    float* rpre2 = ws + OFF_RPRE2;
    float* xi3   = ws + OFF_XI1;     // layer-1 region dead after f2 (kernel boundary)
    float* rpre3 = ws + OFF_RPRE1;
    unsigned short* a1h = (unsigned short*)(ws + OFF_APKH);  // aliases xi2 (dead now)
    unsigned short* a1l = (unsigned short*)(ws + OFF_APKL);
    unsigned short* a2h = (unsigned short*)(ws + OFF_A2H);
    unsigned short* a2l = (unsigned short*)(ws + OFF_A2L);
    unsigned short* a3h = (unsigned short*)(ws + OFF_A3H);
    unsigned short* a3l = (unsigned short*)(ws + OFF_A3L);

    prep_all<<<28, 256, 0, stream>>>(ws);
    prep_apk<<<432, 256, 0, stream>>>(Wi1, Wr1, Wi2, Wr2, Wi3, Wr3,
                                      a1h, a1l, a2h, a2l, a3h, a3l);

    p1_l1_mfma<<<1024, 512, 0, stream>>>(x, a1h, a1l, xi1, rpre1, sum1, sqs1);

    f2_kernel<<<1024, 256, 0, stream>>>(xi1, rpre1, sum1, sqs1, g1, be1, Wsp1,
                                        a2h, a2l, xi2, rpre2, sum2, sqs2);

    f3_kernel<<<1024, 256, 0, stream>>>(xi2, rpre2, sum2, sqs2, g2, be2, Wsp2,
                                        a3h, a3l, xi3, rpre3, sum3, sqs3);

    f4_kernel<<<1024, 256, 0, stream>>>(xi3, rpre3, sum3, sqs3, g3, be3, Wsp3,
                                        Wfc, bfc, out);
}